// Round 4
// baseline (138.573 us; speedup 1.0000x reference)
//
#include <hip/hip_runtime.h>
#include <hip/hip_bf16.h>

#define N_NODES 50000
#define N_EDGES 800000
#define FEAT 64
#define RANGE 32        // nodes per K2 block
#define NBINS 1563      // ceil(50000/32)
#define CAPP 48         // per-node CSR row capacity (deg ~ Poisson(16); P(>48) ~ 1e-11)
#define NCUR 50016      // cursor array padded to int4 multiple (pads zeroed -> deg 0)
#define DUMMY N_NODES   // zero row index for padding slots
#define CONVB 391       // ceil((N_NODES+1)*FEAT/8 / 1024) conv blocks in K1a
#define ZEROB 13        // ceil((NCUR/4)/1024) cursor-zero blocks in K1a

// ============================================================================
// SESSION LEDGER
//  R2 diagnostic: K01 ~6.3us, K2 ~28.8us (2x grid: hbm 30%, VALU 37%, occ 69%,
//     conflicts ~0). Fixed harness floor ~80us. Controllable budget ~35us.
//  R3 FAILED: counts8 + dwordx4 prefetch = noise (115.7 -> 118.5, band +-3).
//     Metadata overfetch was NOT the binding constraint.
//  R4 theory: K2 is bound by per-block serial DS-pipe structure (1640
//     conflicting LDS atomics in fine-sort + 16KB/2KB-live sparse prefetch +
//     3 barriers). Fix: node-granular padded CSR built in K1 via global
//     atomics (cursor[50K] in L2). K2 loses sort/atomics/counts entirely:
//     contiguous 6KB stage, per-slot deg guard, ONE barrier. ent fetch
//     25.6 -> 9.6MB. Predict K2 ~16us, dur ~104.
// ============================================================================

static __device__ __forceinline__ unsigned short f2bu(float f) {
    __hip_bfloat16 h = __float2bfloat16(f);
    return __builtin_bit_cast(unsigned short, h);
}

// K1a: fused conv (fp32->bf16 + zeroed dummy row) + cursor zeroing.
// Both are pure independent writes; scatter (K1b) is a separate dispatch so
// all cursor zeros land before any atomic (no cross-block ordering assumed).
__global__ __launch_bounds__(1024) void conv_zero_kernel(
    const float* __restrict__ src_feat,
    unsigned short* __restrict__ src16,
    int* __restrict__ cursor)
{
    int tid = threadIdx.x;
    if (blockIdx.x < CONVB) {
        int base = (blockIdx.x * 1024 + tid) * 8;
        if (base >= (N_NODES + 1) * FEAT) return;
        uint4 o;
        if (base < N_NODES * FEAT) {
            float4 a = *(const float4*)(src_feat + base);
            float4 b = *(const float4*)(src_feat + base + 4);
            o.x = (unsigned)f2bu(a.x) | ((unsigned)f2bu(a.y) << 16);
            o.y = (unsigned)f2bu(a.z) | ((unsigned)f2bu(a.w) << 16);
            o.z = (unsigned)f2bu(b.x) | ((unsigned)f2bu(b.y) << 16);
            o.w = (unsigned)f2bu(b.z) | ((unsigned)f2bu(b.w) << 16);
        } else {
            o = make_uint4(0, 0, 0, 0);
        }
        *(uint4*)(src16 + base) = o;
        return;
    }
    int idx = (blockIdx.x - CONVB) * 1024 + tid;
    if (idx < NCUR / 4) ((int4*)cursor)[idx] = make_int4(0, 0, 0, 0);
}

// K1b: scatter-bin straight to node-granular padded CSR. 800K global
// atomicAdds on 200KB of L2-resident counters (random dst -> no hotspot),
// plus the same scattered 4B entry writes the old bin kernel did. No LDS,
// no barriers; 4 independent atomic->store chains per thread.
__global__ __launch_bounds__(1024) void scatter_kernel(
    const int* __restrict__ edge_src,
    const int* __restrict__ edge_dst,
    int* __restrict__ cursor,
    int* __restrict__ ent2)        // [NCUR][CAPP]
{
    int t = blockIdx.x * 1024 + threadIdx.x;
    if (t >= N_EDGES / 4) return;
    int4 s4 = ((const int4*)edge_src)[t];
    int4 d4 = ((const int4*)edge_dst)[t];
    int p0 = atomicAdd(&cursor[d4.x], 1);
    int p1 = atomicAdd(&cursor[d4.y], 1);
    int p2 = atomicAdd(&cursor[d4.z], 1);
    int p3 = atomicAdd(&cursor[d4.w], 1);
    if (p0 < CAPP) ent2[(size_t)d4.x * CAPP + p0] = s4.x;
    if (p1 < CAPP) ent2[(size_t)d4.y * CAPP + p1] = s4.y;
    if (p2 < CAPP) ent2[(size_t)d4.z * CAPP + p2] = s4.z;
    if (p3 < CAPP) ent2[(size_t)d4.w * CAPP + p3] = s4.w;
}

// Phase-B pipeline macros — all array indices compile-time (rule #20).
// Guard is per-slot (q*4+sub < deg): replaces the old DUMMY padding pass;
// slots past deg hold ws poison and are selected out.
#define RDIDX(ID, Q)                                                          \
    _Pragma("unroll")                                                         \
    for (int m_ = 0; m_ < 4; ++m_) {                                          \
        int raw_ = ids[(wave * 4 + m_) * CAPP + (Q) * 4 + sub];               \
        ID[m_] = ((Q) * 4 + sub < dg[m_]) ? raw_ : DUMMY;                     \
    }
#define GLOAD(L, ID)                                                          \
    _Pragma("unroll")                                                         \
    for (int m_ = 0; m_ < 4; ++m_)                                            \
        L[m_] = *(const uint2*)(src16 + (size_t)ID[m_] * FEAT + fc * 4);
#define ACCUM(L)                                                              \
    _Pragma("unroll")                                                         \
    for (int m_ = 0; m_ < 4; ++m_) {                                          \
        acc[m_][0] += __uint_as_float(L[m_].x << 16);                         \
        acc[m_][1] += __uint_as_float(L[m_].x & 0xFFFF0000u);                 \
        acc[m_][2] += __uint_as_float(L[m_].y << 16);                         \
        acc[m_][3] += __uint_as_float(L[m_].y & 0xFFFF0000u);                 \
    }

// K2: sort-free. Stage the block's CONTIGUOUS 6KB CSR span + 32 degrees ->
// ONE barrier -> 2-deep pipelined 4-rows-per-load gather with register
// accumulation -> butterfly reduce -> fused 8x8x8 matmul. Zero atomics.
__global__ __launch_bounds__(512, 6) void gather_mm_kernel(
    const unsigned short* __restrict__ src16,
    const float* __restrict__ dst_feat,
    const int* __restrict__ cursor,
    const int* __restrict__ ent2,
    float* __restrict__ out)
{
    __shared__ int ids[RANGE * CAPP];   // 6144 B, direct-mapped [node][slot]
    __shared__ int degs_s[RANGE];

    int r = blockIdx.x;
    int tid = threadIdx.x;
    int wave = tid >> 6;
    int lane = tid & 63;

    // Stage: 384 int4 loads, fully coalesced (block span is contiguous).
    const int4* gsrc = (const int4*)(ent2 + (size_t)r * RANGE * CAPP);
    if (tid < RANGE * CAPP / 4) ((int4*)ids)[tid] = gsrc[tid];
    if (tid < RANGE) {
        int d = cursor[r * RANGE + tid];    // one 128B line per block
        degs_s[tid] = (d > CAPP) ? CAPP : d;
    }

    // dst rows: consumed only in the epilogue (latency free).
    float Bv[4];
    #pragma unroll
    for (int m = 0; m < 4; ++m) {
        int n = r * RANGE + wave * 4 + m;
        Bv[m] = (n < N_NODES) ? dst_feat[n * FEAT + lane] : 0.f;
    }
    __syncthreads();

    // Phase B: wide gather, 2-deep pipelined. Lane covers row-slot (lane>>4),
    // features (lane&15)*4. One dwordx2 load = 4 rows x 128B per wave-instr.
    int sub = lane >> 4;
    int fc  = lane & 15;
    int dg[4], rows4[4], qmax = 0;
    #pragma unroll
    for (int m = 0; m < 4; ++m) {
        dg[m] = degs_s[wave * 4 + m];
        rows4[m] = (dg[m] + 3) >> 2;
        qmax = (rows4[m] > qmax) ? rows4[m] : qmax;
    }

    float acc[4][4] = {{0.f,0.f,0.f,0.f},{0.f,0.f,0.f,0.f},
                       {0.f,0.f,0.f,0.f},{0.f,0.f,0.f,0.f}};
    {
        int idA[4], idB[4];
        uint2 LA[4], LB[4];
        if (qmax > 0) { RDIDX(idA, 0); GLOAD(LA, idA); }
        int q = 0;
        while (q < qmax) {           // qmax wave-uniform -> no divergence
            int qn = q + 1;
            if (qn < qmax) { RDIDX(idB, qn); GLOAD(LB, idB); }
            ACCUM(LA);
            q = qn;
            if (q >= qmax) break;
            qn = q + 1;
            if (qn < qmax) { RDIDX(idA, qn); GLOAD(LA, idA); }
            ACCUM(LB);
            q = qn;
        }
    }

    // Butterfly-reduce the 4 row-slots: all lanes end with full sums for
    // features fc*4+u of node m.
    #pragma unroll
    for (int m = 0; m < 4; ++m) {
        #pragma unroll
        for (int u = 0; u < 4; ++u) {
            acc[m][u] += __shfl_xor(acc[m][u], 16, 64);
            acc[m][u] += __shfl_xor(acc[m][u], 32, 64);
        }
    }

    // Epilogue: 8x8 matmul. S feature 8i+p lives in lane 2i+(p>>2), reg p&3.
    int i = lane >> 3;
    int j = lane & 7;
    #pragma unroll
    for (int m = 0; m < 4; ++m) {
        int n = r * RANGE + wave * 4 + m;
        if (n >= N_NODES) break;
        float res = 0.0f;
        #pragma unroll
        for (int p = 0; p < 8; ++p) {
            float s_ip = __shfl(acc[m][p & 3], 2 * i + (p >> 2), 64);
            float b_pj = __shfl(Bv[m], p * 8 + j, 64);
            res += s_ip * b_pj;
        }
        out[n * FEAT + lane] = res * 0.35355339059327373f;  // 1/sqrt(8)
    }
}

extern "C" void kernel_launch(void* const* d_in, const int* in_sizes, int n_in,
                              void* d_out, int out_size, void* d_ws, size_t ws_size,
                              hipStream_t stream) {
    const float* src_feat = (const float*)d_in[0];
    const float* dst_feat = (const float*)d_in[1];
    const int* edge_src = (const int*)d_in[2];
    const int* edge_dst = (const int*)d_in[3];
    float* out = (float*)d_out;

    // ws layout: cursor [NCUR] ints              =   200,064 B
    //            ent2   [NCUR][CAPP] ints        = 9,603,072 B
    //            src16  (N_NODES+1)*FEAT u16     = 6,400,128 B   (~16.2 MB)
    char* w = (char*)d_ws;
    int* cursor = (int*)w;                        w += (size_t)NCUR * 4;
    int* ent2 = (int*)w;                          w += (size_t)NCUR * CAPP * 4;
    unsigned short* src16 = (unsigned short*)w;

    conv_zero_kernel<<<CONVB + ZEROB, 1024, 0, stream>>>(src_feat, src16, cursor);

    scatter_kernel<<<196, 1024, 0, stream>>>(edge_src, edge_dst, cursor, ent2);

    gather_mm_kernel<<<NBINS, 512, 0, stream>>>(src16, dst_feat, cursor, ent2, out);
}

// Round 5
// 117.666 us; speedup vs baseline: 1.1777x; 1.1777x over previous
//
#include <hip/hip_runtime.h>
#include <hip/hip_bf16.h>

#define N_NODES 50000
#define N_EDGES 800000
#define FEAT 64
#define RANGE 32        // nodes per K2 block
#define NBINS 1563      // ceil(50000/32)
#define K1B 250         // bin blocks; EPB = 3200 (multiple of 4)
#define EPB (N_EDGES / K1B)
#define SUB 8           // slots per (range, bin-block) chunk; fill ~ Poisson(2.05)
                        // P(chunk>8)~2.8e-4 -> ~130 overflow edges -> ovf list
#define RSTRIDE 2048    // ent ints per range: 256 padded chunks x 8 (guard-free prefetch)
#define CAPP 48         // per-node bucket capacity (deg ~ Poisson(16); P(>48) ~ 1e-11)
#define BSTRIDE 52      // bucket row stride in ints (16B-aligned, odd bank step)
#define DUMMY N_NODES   // zero row index for degree padding
#define CONVB 391       // ceil((N_NODES+1)*FEAT/8 / 1024) conv blocks in fused K01
#define OVF_CAP 16      // per-bin-block overflow capacity (expect 0.5, P(>16)~1e-20)

// ============================================================================
// SESSION LEDGER
//  R2 diagnostic: K01 ~6.3us, K2 ~28.8us (2x grid: FETCH 112MB, VALU 37%,
//     hbm 30%, occ 69%, conflicts ~0). Harness floor ~80us. Budget ~35us.
//  R3 NEUTRAL: counts8 + dwordx4 prefetch = noise (118.5). BW not binding.
//  R4 REGRESSION (138.6): node-CSR via 800K device-scope global atomics +
//     scattered partial-line stores >> LDS binning. REVERTED.
//  R5 theory: K2 latency/issue-bound but every path scales with ent volume
//     (25.6MB = 46% of K2 fetch, 12.5% fill). SUB 16->8 halves ent stream,
//     prefetch regs, and filter predicates; rare chunk overflows (~130 edges)
//     preserved via block-local ovf list (no ordering dep, no extra dispatch).
//     Predict K2 ~22-24us, dur ~108-112.
// ============================================================================

static __device__ __forceinline__ unsigned short f2bu(float f) {
    __hip_bfloat16 h = __float2bfloat16(f);
    return __builtin_bit_cast(unsigned short, h);
}

// K01: fused conv + bin (16 waves/CU bin part; conv overlaps bin).
__global__ __launch_bounds__(1024) void conv_bin_kernel(
    const float* __restrict__ src_feat,
    unsigned short* __restrict__ src16,
    const int* __restrict__ edge_src,
    const int* __restrict__ edge_dst,
    unsigned char* __restrict__ counts8,  // [K1B][NBINS] u8 (b-major publish)
    int* __restrict__ ent,                // [NBINS][RSTRIDE]; chunk (r,b) at r*2048+b*8
    int2* __restrict__ ovf,               // [K1B][OVF_CAP] (dst, src) pairs
    int* __restrict__ ovfcnt)             // [K1B]
{
    __shared__ int h[NBINS];        // 6.25 KB cursors (bin blocks only)
    __shared__ int ovfc;
    int tid = threadIdx.x;

    if (blockIdx.x < CONVB) {
        // ---- conv part: 8 floats -> 8 bf16 per thread ----
        int base = (blockIdx.x * 1024 + tid) * 8;
        if (base >= (N_NODES + 1) * FEAT) return;
        uint4 o;
        if (base < N_NODES * FEAT) {
            float4 a = *(const float4*)(src_feat + base);
            float4 b = *(const float4*)(src_feat + base + 4);
            o.x = (unsigned)f2bu(a.x) | ((unsigned)f2bu(a.y) << 16);
            o.y = (unsigned)f2bu(a.z) | ((unsigned)f2bu(a.w) << 16);
            o.z = (unsigned)f2bu(b.x) | ((unsigned)f2bu(b.y) << 16);
            o.w = (unsigned)f2bu(b.z) | ((unsigned)f2bu(b.w) << 16);
        } else {
            o = make_uint4(0, 0, 0, 0);
        }
        *(uint4*)(src16 + base) = o;
        return;
    }

    // ---- bin part: deterministic single-pass binning ----
    int b = blockIdx.x - CONVB;
    for (int r = tid; r < NBINS; r += 1024) h[r] = 0;
    if (tid == 0) ovfc = 0;
    __syncthreads();

    if (tid < EPB / 4) {            // exactly 800 threads, one int4 each
        int e = b * EPB + tid * 4;
        int4 s4 = *(const int4*)(edge_src + e);
        int4 d4 = *(const int4*)(edge_dst + e);
        int r0 = d4.x >> 5, r1 = d4.y >> 5, r2 = d4.z >> 5, r3 = d4.w >> 5;
        int p0 = atomicAdd(&h[r0], 1);
        int p1 = atomicAdd(&h[r1], 1);
        int p2 = atomicAdd(&h[r2], 1);
        int p3 = atomicAdd(&h[r3], 1);
        if (p0 < SUB) ent[r0 * RSTRIDE + b * SUB + p0] = ((d4.x & 31) << 16) | s4.x;
        else { int op = atomicAdd(&ovfc, 1); if (op < OVF_CAP) ovf[b * OVF_CAP + op] = make_int2(d4.x, s4.x); }
        if (p1 < SUB) ent[r1 * RSTRIDE + b * SUB + p1] = ((d4.y & 31) << 16) | s4.y;
        else { int op = atomicAdd(&ovfc, 1); if (op < OVF_CAP) ovf[b * OVF_CAP + op] = make_int2(d4.y, s4.y); }
        if (p2 < SUB) ent[r2 * RSTRIDE + b * SUB + p2] = ((d4.z & 31) << 16) | s4.z;
        else { int op = atomicAdd(&ovfc, 1); if (op < OVF_CAP) ovf[b * OVF_CAP + op] = make_int2(d4.z, s4.z); }
        if (p3 < SUB) ent[r3 * RSTRIDE + b * SUB + p3] = ((d4.w & 31) << 16) | s4.w;
        else { int op = atomicAdd(&ovfc, 1); if (op < OVF_CAP) ovf[b * OVF_CAP + op] = make_int2(d4.w, s4.w); }
    }
    __syncthreads();

    // Publish counts as BYTES (b-major, contiguous) + this block's ovf count.
    for (int r = tid; r < NBINS; r += 1024) {
        int c = h[r];
        counts8[(size_t)b * NBINS + r] = (unsigned char)((c > SUB) ? SUB : c);
    }
    if (tid == 0) {
        int oc = ovfc;
        ovfcnt[b] = (oc > OVF_CAP) ? OVF_CAP : oc;
    }
}

// Phase-B pipeline macros — all array indices compile-time (rule #20).
#define RDIDX(ID, Q)                                                          \
    _Pragma("unroll")                                                         \
    for (int m_ = 0; m_ < 4; ++m_) {                                          \
        int raw_ = bucket_w[(wave * 4 + m_) * BSTRIDE + (Q) * 4 + sub];       \
        ID[m_] = ((Q) < rows4[m_]) ? raw_ : DUMMY;                            \
    }
#define GLOAD(L, ID)                                                          \
    _Pragma("unroll")                                                         \
    for (int m_ = 0; m_ < 4; ++m_)                                            \
        L[m_] = *(const uint2*)(src16 + (size_t)ID[m_] * FEAT + fc * 4);
#define ACCUM(L)                                                              \
    _Pragma("unroll")                                                         \
    for (int m_ = 0; m_ < 4; ++m_) {                                          \
        acc[m_][0] += __uint_as_float(L[m_].x << 16);                         \
        acc[m_][1] += __uint_as_float(L[m_].x & 0xFFFF0000u);                 \
        acc[m_][2] += __uint_as_float(L[m_].y << 16);                         \
        acc[m_][3] += __uint_as_float(L[m_].y & 0xFFFF0000u);                 \
    }

// K2: guard-free ent prefetch (1x dwordx4/thread, SUB=8) -> LDS fine-sort ->
// rare ovf merge -> 2-deep pipelined 4-rows-per-load gather -> butterfly
// reduce -> fused 8x8x8 matmul.
__global__ __launch_bounds__(512, 6) void sort_gather_mm_kernel(
    const unsigned short* __restrict__ src16,
    const float* __restrict__ dst_feat,
    const unsigned char* __restrict__ counts8,
    const int* __restrict__ ent,
    const int2* __restrict__ ovf,
    const int* __restrict__ ovfcnt,
    float* __restrict__ out)
{
    __shared__ int bucket_w[RANGE * BSTRIDE];   // 6656 B
    __shared__ int cnt_s[256];                  // 250 real + 6 zero pads
    __shared__ int c[RANGE];

    int r = blockIdx.x;
    int tid = threadIdx.x;
    int wave = tid >> 6;
    int lane = tid & 63;

    // Unconditional ent prefetch: ONE dwordx4 per thread (2048 slots total).
    // tid*4 % 8 in {0,4} -> each int4 lies in one chunk: count uniform/quad.
    const int* er = ent + (size_t)r * RSTRIDE;
    int4 ew = *(const int4*)(er + tid * 4);

    // counts: 250 scattered BYTE reads ([b][r] layout), L2/L3-line-shared
    // across 64 consecutive r-blocks.
    if (tid < 256) cnt_s[tid] = (tid < K1B) ? (int)counts8[(size_t)tid * NBINS + r] : 0;
    if (tid < RANGE) c[tid] = 0;

    // dst rows: consumed only in the epilogue (latency free).
    float Bv[4];
    #pragma unroll
    for (int m = 0; m < 4; ++m) {
        int n = r * RANGE + wave * 4 + m;
        Bv[m] = (n < N_NODES) ? dst_feat[n * FEAT + lane] : 0.f;
    }
    __syncthreads();

    // Phase A: filter prefetched slots, sort into per-node u32 buckets.
    {
        int base = tid * 4;
        int bb = base >> 3;           // chunk index (uniform over the quad)
        int s0 = base & 7;            // 0 or 4
        int cnt = cnt_s[bb];
        int vals[4] = {ew.x, ew.y, ew.z, ew.w};
        #pragma unroll
        for (int j = 0; j < 4; ++j) {
            if (s0 + j < cnt) {
                int p = vals[j];
                int dl = p >> 16;
                int pos = atomicAdd(&c[dl], 1);
                if (pos < CAPP) bucket_w[dl * BSTRIDE + pos] = p & 0xFFFF;
            }
        }
    }
    // Rare overflow merge: 250 contiguous counts, almost always zero.
    if (tid < K1B) {
        int oc = ovfcnt[tid];
        for (int e = 0; e < oc; ++e) {
            int2 pr = ovf[tid * OVF_CAP + e];
            if ((pr.x >> 5) == r) {
                int dl = pr.x & 31;
                int pos = atomicAdd(&c[dl], 1);
                if (pos < CAPP) bucket_w[dl * BSTRIDE + pos] = pr.y;
            }
        }
    }
    __syncthreads();

    // Pad each node's count to a multiple of 4 with the zero dummy row.
    if (tid < RANGE) {
        int cc = c[tid]; if (cc > CAPP) cc = CAPP;
        while (cc & 3) bucket_w[tid * BSTRIDE + cc++] = DUMMY;
        c[tid] = cc >> 2;             // rows-of-4 count
    }
    __syncthreads();

    // Phase B: wide gather, 2-deep pipelined. Lane covers row-slot (lane>>4),
    // features (lane&15)*4. One dwordx2 load = 4 rows x 128B per wave-instr.
    int sub = lane >> 4;
    int fc  = lane & 15;
    int rows4[4], qmax = 0;
    #pragma unroll
    for (int m = 0; m < 4; ++m) {
        rows4[m] = c[wave * 4 + m];
        qmax = (rows4[m] > qmax) ? rows4[m] : qmax;
    }

    float acc[4][4] = {{0.f,0.f,0.f,0.f},{0.f,0.f,0.f,0.f},
                       {0.f,0.f,0.f,0.f},{0.f,0.f,0.f,0.f}};
    {
        int idA[4], idB[4];
        uint2 LA[4], LB[4];
        if (qmax > 0) { RDIDX(idA, 0); GLOAD(LA, idA); }
        int q = 0;
        while (q < qmax) {           // qmax wave-uniform -> no divergence
            int qn = q + 1;
            if (qn < qmax) { RDIDX(idB, qn); GLOAD(LB, idB); }
            ACCUM(LA);
            q = qn;
            if (q >= qmax) break;
            qn = q + 1;
            if (qn < qmax) { RDIDX(idA, qn); GLOAD(LA, idA); }
            ACCUM(LB);
            q = qn;
        }
    }

    // Butterfly-reduce the 4 row-slots.
    #pragma unroll
    for (int m = 0; m < 4; ++m) {
        #pragma unroll
        for (int u = 0; u < 4; ++u) {
            acc[m][u] += __shfl_xor(acc[m][u], 16, 64);
            acc[m][u] += __shfl_xor(acc[m][u], 32, 64);
        }
    }

    // Epilogue: 8x8 matmul. S feature 8i+p lives in lane 2i+(p>>2), reg p&3.
    int i = lane >> 3;
    int j = lane & 7;
    #pragma unroll
    for (int m = 0; m < 4; ++m) {
        int n = r * RANGE + wave * 4 + m;
        if (n >= N_NODES) break;
        float res = 0.0f;
        #pragma unroll
        for (int p = 0; p < 8; ++p) {
            float s_ip = __shfl(acc[m][p & 3], 2 * i + (p >> 2), 64);
            float b_pj = __shfl(Bv[m], p * 8 + j, 64);
            res += s_ip * b_pj;
        }
        out[n * FEAT + lane] = res * 0.35355339059327373f;  // 1/sqrt(8)
    }
}

extern "C" void kernel_launch(void* const* d_in, const int* in_sizes, int n_in,
                              void* d_out, int out_size, void* d_ws, size_t ws_size,
                              hipStream_t stream) {
    const float* src_feat = (const float*)d_in[0];
    const float* dst_feat = (const float*)d_in[1];
    const int* edge_src = (const int*)d_in[2];
    const int* edge_dst = (const int*)d_in[3];
    float* out = (float*)d_out;

    // ws layout: counts8 [K1B][NBINS] u8       =   390,752 B (padded)
    //            ovfcnt  [K1B] ints            =     1,024 B (padded)
    //            ovf     [K1B][OVF_CAP] int2   =    32,000 B
    //            ent     [NBINS][RSTRIDE] ints = 12,804,096 B
    //            src16   (N_NODES+1)*FEAT u16  =  6,400,128 B   (~19.6 MB)
    char* w = (char*)d_ws;
    unsigned char* counts8 = (unsigned char*)w;   w += 390752;
    int* ovfcnt = (int*)w;                        w += 1024;
    int2* ovf = (int2*)w;                         w += (size_t)K1B * OVF_CAP * 8;
    int* ent = (int*)w;                           w += (size_t)NBINS * RSTRIDE * 4;
    unsigned short* src16 = (unsigned short*)w;

    conv_bin_kernel<<<CONVB + K1B, 1024, 0, stream>>>(
        src_feat, src16, edge_src, edge_dst, counts8, ent, ovf, ovfcnt);

    sort_gather_mm_kernel<<<NBINS, 512, 0, stream>>>(
        src16, dst_feat, counts8, ent, ovf, ovfcnt, out);
}